// Round 12
// baseline (156.844 us; speedup 1.0000x reference)
//
#include <hip/hip_runtime.h>
#include <stdint.h>

#define BATCH 32
#define CH    256
#define TLEN  4096
#define TN    32            // timesteps per tile
#define NT    8             // tiles per block (block covers 256 t)
#define RNG   64            // sA ring rows (power of 2 -> free mod)
#define SST   36            // phase-B f32 scratch row stride

typedef short    bf16x8 __attribute__((ext_vector_type(8)));
typedef float    f32x4  __attribute__((ext_vector_type(4)));
typedef uint16_t u16x4  __attribute__((ext_vector_type(4)));

// packed fragment-order weights: g_wpk[(s*CH + co)*32 + g*8 + e] = w1eff[co][32s+8g+e]
__device__ __attribute__((aligned(16))) uint16_t g_wpk[CH * CH];
__device__ __attribute__((aligned(16))) float g_tap[5 * CH];   // tap-major
__device__ __attribute__((aligned(16))) float g_bias[CH];

static __device__ __forceinline__ uint16_t f32_to_bf16(float f) {
    uint32_t u = __builtin_bit_cast(uint32_t, f);
    u += 0x7FFFu + ((u >> 16) & 1u);
    return (uint16_t)(u >> 16);
}
static __device__ __forceinline__ float bf16_to_f32(uint16_t h) {
    uint32_t u = ((uint32_t)h) << 16;
    return __builtin_bit_cast(float, u);
}
// ring-row XOR swizzle (8 distinct values across rows stepping by 4)
static __device__ __forceinline__ int swzr(int row) {
    return ((row ^ (row >> 2)) & 7) << 3;
}
// tanh-form gelu folded into exp2
static __device__ __forceinline__ float gelu_fast(float x) {
    const float A = 2.3022082f;
    const float B = 0.10294331f;
    float x2 = x * x;
    float z  = x * fmaf(x2, B, A);
    float e  = exp2f(z);
    float r  = __builtin_amdgcn_rcpf(1.0f + e);
    return fmaf(-x, r, x);
}

__global__ void prep_kernel(const float* __restrict__ w1, const float* __restrict__ b1,
                            const float* __restrict__ w3, const float* __restrict__ b3,
                            const float* __restrict__ w5, const float* __restrict__ b5,
                            const float* __restrict__ wc, const float* __restrict__ bc) {
    const int o = blockIdx.x;
    const int c = threadIdx.x;
    const float wc0 = wc[o * 3 + 0];
    // fragment-order pack: s = k>>5 (K-chunk), g = (k>>3)&3 (kgrp quad), e = k&7
    const int s = c >> 5, g = (c >> 3) & 3, e = c & 7;
    g_wpk[(s * CH + o) * 32 + g * 8 + e] = f32_to_bf16(wc0 * w1[o * CH + c]);
    if (c == 0) {
        const float wc1 = wc[o * 3 + 1], wc2 = wc[o * 3 + 2];
        g_tap[0 * CH + o] = wc2 * w5[o * 5 + 0];
        g_tap[1 * CH + o] = wc1 * w3[o * 3 + 0] + wc2 * w5[o * 5 + 1];
        g_tap[2 * CH + o] = wc1 * w3[o * 3 + 1] + wc2 * w5[o * 5 + 2];
        g_tap[3 * CH + o] = wc1 * w3[o * 3 + 2] + wc2 * w5[o * 5 + 3];
        g_tap[4 * CH + o] = wc2 * w5[o * 5 + 4];
        g_bias[o] = wc0 * b1[o] + wc1 * b3[o] + wc2 * b5[o] + bc[o];
    }
}

// Persistent t-march: block = (batch b, 256-t strip), 8 tiles of 32 t.
// Weights: per-wave 64-out-channel panel held ENTIRELY in VGPRs (wfr[8][4],
// 128 VGPRs), loaded once via coalesced 1KB wave-loads from g_wpk.
// sA ring: row rho(tau) = (tau - t0b + 2) & 63 = bf16(gelu(x)), col c^swzr(row).
// K-loop per tile: {2 ds_read_b128 + 8 MFMA} per step — no global loads.
__global__ __launch_bounds__(256, 2)
void fused_kernel(const float* __restrict__ x, float* __restrict__ out) {
    __shared__ __attribute__((aligned(16))) uint16_t sA[RNG * CH];      // 32768 B
    __shared__ __attribute__((aligned(16))) float    sS[4 * 16 * SST];  //  9216 B

    const int tid  = threadIdx.x;
    const int lane = tid & 63;
    const int wid  = tid >> 6;
    const int b    = blockIdx.y;
    const int t0b  = blockIdx.x * (TN * NT);

    const float* __restrict__ xb = x + (size_t)b * CH * TLEN;
    float* __restrict__ ob = out + (size_t)b * CH * TLEN;

    const int colt = lane & 15;
    const int rg   = (lane >> 4) * 4;
    const int kgrp = (lane >> 4) * 8;
    const int m0   = wid * 64;

    // ---- prologue: whole weight panel into registers (32 coalesced 1KB loads) ----
    bf16x8 wfr[8][4];
#pragma unroll
    for (int s = 0; s < 8; ++s)
#pragma unroll
        for (int mi = 0; mi < 4; ++mi) {
            const int co = m0 + mi * 16 + colt;
            wfr[s][mi] = *(const bf16x8*)(g_wpk + (s * CH + co) * 32 + kgrp);
        }

    // ---- prologue edge: rows 0..3  <-> tau = t0b-2 .. t0b+1, c = tid ----
    {
        const int c = tid;
        float v[4];
        if (blockIdx.x == 0) {
#pragma unroll
            for (int j = 0; j < 4; ++j) {
                const int gt = t0b - 2 + j;
                v[j] = (gt >= 0) ? xb[(size_t)c * TLEN + gt] : 0.0f;
            }
        } else {
            f32x4 vv = *(const f32x4*)(xb + (size_t)c * TLEN + (t0b - 2));
            v[0] = vv[0]; v[1] = vv[1]; v[2] = vv[2]; v[3] = vv[3];
        }
#pragma unroll
        for (int j = 0; j < 4; ++j)
            sA[j * CH + (c ^ swzr(j))] = f32_to_bf16(gelu_fast(v[j]));
    }

    const int cs = lane >> 3;       // channel-sub within wave
    const int q  = lane & 7;        // t-quad
    const int c0 = wid * 64;

    // ---- prologue prefetch: tau in [t0b+2, t0b+34) ----
    f32x4 vreg[8];
    {
        const int ts = t0b + 2 + q * 4;
#pragma unroll
        for (int r = 0; r < 8; ++r) {
            const int c = c0 + r * 8 + cs;
            vreg[r] = *(const f32x4*)(xb + (size_t)c * TLEN + ts);
        }
    }

    const int ci = lane >> 2;
    const int qq = lane & 3;
    float* __restrict__ sw = sS + wid * (16 * SST);

    for (int i = 0; i < NT; ++i) {
        // ---- STAGE: write gelu(vreg) into ring rows (32i+4 .. 32i+35)&63 ----
        {
            const int rb4 = (32 * i + 4) & 63;
#pragma unroll
            for (int r = 0; r < 8; ++r) {
                const int c = c0 + r * 8 + cs;
#pragma unroll
                for (int j = 0; j < 4; ++j) {
                    const int row = (rb4 + q * 4 + j) & 63;
                    sA[row * CH + (c ^ swzr(row))] = f32_to_bf16(gelu_fast(vreg[r][j]));
                }
            }
        }
        __syncthreads();   // B1: tile data visible to all waves

        // ---- PREFETCH tile i+1 (overlaps K-loop + epilogue) ----
        if (i + 1 < NT) {
            const int ts = t0b + 32 * (i + 1) + 2 + q * 4;
            if (ts + 4 <= TLEN) {
#pragma unroll
                for (int r = 0; r < 8; ++r) {
                    const int c = c0 + r * 8 + cs;
                    vreg[r] = *(const f32x4*)(xb + (size_t)c * TLEN + ts);
                }
            } else {
#pragma unroll
                for (int r = 0; r < 8; ++r) {
                    const int c = c0 + r * 8 + cs;
#pragma unroll
                    for (int j = 0; j < 4; ++j)
                        vreg[r][j] = (ts + j < TLEN) ? xb[(size_t)c * TLEN + ts + j] : 0.0f;
                }
            }
        }

        // ---- K-loop: B-frags from LDS ring (ping-pong), weights from VGPRs ----
        int rowB[2], swzB[2];
#pragma unroll
        for (int ni = 0; ni < 2; ++ni) {
            const int row = (32 * i + 2 + ni * 16 + colt) & 63;
            rowB[ni] = row * CH;
            swzB[ni] = swzr(row);
        }

        f32x4 acc[4][2];
        const f32x4 vzero = {0.f, 0.f, 0.f, 0.f};
#pragma unroll
        for (int mi = 0; mi < 4; ++mi)
#pragma unroll
            for (int ni = 0; ni < 2; ++ni) acc[mi][ni] = vzero;

        bf16x8 bfb[2][2];
#pragma unroll
        for (int ni = 0; ni < 2; ++ni)
            bfb[0][ni] = *(const bf16x8*)(&sA[rowB[ni] + (kgrp ^ swzB[ni])]);
#pragma unroll
        for (int s = 0; s < 8; ++s) {
            const int cur = s & 1, nxt = cur ^ 1;
            if (s < 7) {
                const int cin = (s + 1) * 32 + kgrp;
#pragma unroll
                for (int ni = 0; ni < 2; ++ni)
                    bfb[nxt][ni] = *(const bf16x8*)(&sA[rowB[ni] + (cin ^ swzB[ni])]);
            }
#pragma unroll
            for (int mi = 0; mi < 4; ++mi)
#pragma unroll
                for (int ni = 0; ni < 2; ++ni)
                    acc[mi][ni] = __builtin_amdgcn_mfma_f32_16x16x32_bf16(wfr[s][mi], bfb[cur][ni], acc[mi][ni], 0, 0, 0);
        }

        // ---- PHASE A: depthwise + bias folded into acc ----
        int rowA[2][5], swzA[2][5];
#pragma unroll
        for (int ni = 0; ni < 2; ++ni)
#pragma unroll
            for (int k = 0; k < 5; ++k) {
                const int row = (32 * i + ni * 16 + colt + k) & 63;
                rowA[ni][k] = row * CH;
                swzA[ni][k] = swzr(row);
            }
#pragma unroll
        for (int mi = 0; mi < 4; ++mi) {
            const int c = m0 + mi * 16 + rg;
            const f32x4 tp0 = *(const f32x4*)(g_tap + 0 * CH + c);
            const f32x4 tp1 = *(const f32x4*)(g_tap + 1 * CH + c);
            const f32x4 tp2 = *(const f32x4*)(g_tap + 2 * CH + c);
            const f32x4 tp3 = *(const f32x4*)(g_tap + 3 * CH + c);
            const f32x4 tp4 = *(const f32x4*)(g_tap + 4 * CH + c);
            const f32x4 bsv = *(const f32x4*)(g_bias + c);
#pragma unroll
            for (int ni = 0; ni < 2; ++ni) {
                u16x4 a0 = *(const u16x4*)(&sA[rowA[ni][0] + (c ^ swzA[ni][0])]);
                u16x4 a1 = *(const u16x4*)(&sA[rowA[ni][1] + (c ^ swzA[ni][1])]);
                u16x4 a2 = *(const u16x4*)(&sA[rowA[ni][2] + (c ^ swzA[ni][2])]);
                u16x4 a3 = *(const u16x4*)(&sA[rowA[ni][3] + (c ^ swzA[ni][3])]);
                u16x4 a4 = *(const u16x4*)(&sA[rowA[ni][4] + (c ^ swzA[ni][4])]);
#pragma unroll
                for (int r = 0; r < 4; ++r) {
                    float d = tp0[r] * bf16_to_f32(a0[r]);
                    d = fmaf(tp1[r], bf16_to_f32(a1[r]), d);
                    d = fmaf(tp2[r], bf16_to_f32(a2[r]), d);
                    d = fmaf(tp3[r], bf16_to_f32(a3[r]), d);
                    d = fmaf(tp4[r], bf16_to_f32(a4[r]), d);
                    acc[mi][ni][r] += d + bsv[r];
                }
            }
        }
        __syncthreads();   // B2: sA reads of tile i done; next STAGE may overwrite

        // ---- PHASE B: residual loads (L2-hot), then wave-private transpose ----
        const int tg0 = t0b + 32 * i;
        f32x4 xv[4][2];
#pragma unroll
        for (int mi = 0; mi < 4; ++mi) {
            const int cc = m0 + mi * 16 + ci;
            const float* xrow = xb + (size_t)cc * TLEN + tg0 + qq * 8;
            xv[mi][0] = *(const f32x4*)(xrow + 0);
            xv[mi][1] = *(const f32x4*)(xrow + 4);
        }
#pragma unroll
        for (int mi = 0; mi < 4; ++mi) {
#pragma unroll
            for (int ni = 0; ni < 2; ++ni) {
                const int t = ni * 16 + colt;
#pragma unroll
                for (int r = 0; r < 4; ++r) sw[(rg + r) * SST + t] = acc[mi][ni][r];
            }
            const int cc = m0 + mi * 16 + ci;
            float* orow = ob + (size_t)cc * TLEN + tg0 + qq * 8;
            const float* srow = sw + ci * SST + qq * 8;
            f32x4 s0 = *(const f32x4*)(srow + 0);
            f32x4 s1 = *(const f32x4*)(srow + 4);
            *(f32x4*)(orow + 0) = s0 + xv[mi][0];
            *(f32x4*)(orow + 4) = s1 + xv[mi][1];
        }
    }
}

extern "C" void kernel_launch(void* const* d_in, const int* in_sizes, int n_in,
                              void* d_out, int out_size, void* d_ws, size_t ws_size,
                              hipStream_t stream) {
    const float* x  = (const float*)d_in[0];
    const float* w1 = (const float*)d_in[1];
    const float* b1 = (const float*)d_in[2];
    const float* w3 = (const float*)d_in[3];
    const float* b3 = (const float*)d_in[4];
    const float* w5 = (const float*)d_in[5];
    const float* b5 = (const float*)d_in[6];
    const float* wc = (const float*)d_in[7];
    const float* bc = (const float*)d_in[8];
    float* out = (float*)d_out;

    prep_kernel<<<dim3(CH), dim3(CH), 0, stream>>>(w1, b1, w3, b3, w5, b5, wc, bc);
    fused_kernel<<<dim3(TLEN / (TN * NT), BATCH), dim3(256), 0, stream>>>(x, out);
}

// Round 13
// 127.134 us; speedup vs baseline: 1.2337x; 1.2337x over previous
//
#include <hip/hip_runtime.h>
#include <stdint.h>

#define BATCH 32
#define CH    256
#define TLEN  4096
#define TN    64
#define TPAD  4100          // aT rows per batch strip: 2 pad + 4096 + 2 pad
#define SST   68            // phase-B f32 scratch row stride

typedef short    bf16x8 __attribute__((ext_vector_type(8)));
typedef float    f32x4  __attribute__((ext_vector_type(4)));
typedef uint16_t u16x4  __attribute__((ext_vector_type(4)));
typedef uint16_t u16x8  __attribute__((ext_vector_type(8)));

__device__ __attribute__((aligned(16))) uint16_t g_w1eff[CH * CH];
__device__ __attribute__((aligned(16))) float g_tap[5 * CH];   // tap-major
__device__ __attribute__((aligned(16))) float g_bias[CH];

static __device__ __forceinline__ uint16_t f32_to_bf16(float f) {
    uint32_t u = __builtin_bit_cast(uint32_t, f);
    u += 0x7FFFu + ((u >> 16) & 1u);
    return (uint16_t)(u >> 16);
}
static __device__ __forceinline__ float bf16_to_f32(uint16_t h) {
    uint32_t u = ((uint32_t)h) << 16;
    return __builtin_bit_cast(float, u);
}
// tanh-form gelu folded into exp2
static __device__ __forceinline__ float gelu_fast(float x) {
    const float A = 2.3022082f;
    const float B = 0.10294331f;
    float x2 = x * x;
    float z  = x * fmaf(x2, B, A);
    float e  = exp2f(z);
    float r  = __builtin_amdgcn_rcpf(1.0f + e);
    return fmaf(-x, r, x);
}

__global__ void prep_kernel(const float* __restrict__ w1, const float* __restrict__ b1,
                            const float* __restrict__ w3, const float* __restrict__ b3,
                            const float* __restrict__ w5, const float* __restrict__ b5,
                            const float* __restrict__ wc, const float* __restrict__ bc) {
    const int o = blockIdx.x;
    const int c = threadIdx.x;
    const float wc0 = wc[o * 3 + 0];
    g_w1eff[o * CH + c] = f32_to_bf16(wc0 * w1[o * CH + c]);
    if (c == 0) {
        const float wc1 = wc[o * 3 + 1], wc2 = wc[o * 3 + 2];
        g_tap[0 * CH + o] = wc2 * w5[o * 5 + 0];
        g_tap[1 * CH + o] = wc1 * w3[o * 3 + 0] + wc2 * w5[o * 5 + 1];
        g_tap[2 * CH + o] = wc1 * w3[o * 3 + 1] + wc2 * w5[o * 5 + 2];
        g_tap[3 * CH + o] = wc1 * w3[o * 3 + 2] + wc2 * w5[o * 5 + 3];
        g_tap[4 * CH + o] = wc2 * w5[o * 5 + 4];
        g_bias[o] = wc0 * b1[o] + wc1 * b3[o] + wc2 * b5[o] + bc[o];
    }
}

// k1: gelu + cast + transpose into aT[b][strip_row][c] bf16, where
// strip_row = 2 + t, element (t,c) stored at col c ^ ((t&7)<<3).
// Pad rows 0,1 (t=-2,-1) and 4098,4099 (t=4096,4097) zeroed with matching swizzle.
__global__ __launch_bounds__(256, 4)
void gelu_tr_kernel(const float* __restrict__ x, uint16_t* __restrict__ aT) {
    __shared__ __attribute__((aligned(16))) uint16_t sL[64 * 72];   // 9216 B

    const int tid = threadIdx.x;
    const int tb = blockIdx.x, cb = blockIdx.y, b = blockIdx.z;
    const int t0 = tb * 64, c0 = cb * 64;

    // read 64c x 64t f32 tile, gelu, stage to LDS [c][t]
    {
        const int cr = tid >> 2;       // 0..63 channel-local
        const int q  = tid & 3;        // 0..3 t-quarter (16 t)
        const float* xr = x + ((size_t)(b * CH + c0 + cr)) * TLEN + t0 + q * 16;
        f32x4 v0 = *(const f32x4*)(xr + 0);
        f32x4 v1 = *(const f32x4*)(xr + 4);
        f32x4 v2 = *(const f32x4*)(xr + 8);
        f32x4 v3 = *(const f32x4*)(xr + 12);
        u16x8 p0, p1;
#pragma unroll
        for (int j = 0; j < 4; ++j) {
            p0[j]     = f32_to_bf16(gelu_fast(v0[j]));
            p0[4 + j] = f32_to_bf16(gelu_fast(v1[j]));
            p1[j]     = f32_to_bf16(gelu_fast(v2[j]));
            p1[4 + j] = f32_to_bf16(gelu_fast(v3[j]));
        }
        *(u16x8*)(&sL[cr * 72 + q * 16 + 0]) = p0;
        *(u16x8*)(&sL[cr * 72 + q * 16 + 8]) = p1;
    }
    __syncthreads();

    // write transposed rows: chunk = (t-row tr, 8 channels)
    uint16_t* aTb = aT + (size_t)b * TPAD * CH;
#pragma unroll
    for (int i = 0; i < 2; ++i) {
        const int idx = tid + i * 256;
        const int tr  = idx >> 3;      // 0..63
        const int ch  = idx & 7;       // 0..7 c-chunk
        const int t   = t0 + tr;
        const int swz = (t & 7) << 3;
        u16x8 o;
#pragma unroll
        for (int j = 0; j < 8; ++j) o[j] = sL[(ch * 8 + j) * 72 + tr];
        *(u16x8*)(&aTb[(size_t)(2 + t) * CH + ((c0 + ch * 8) ^ swz)]) = o;
    }
    // zero pad rows (once per (b, cb), by tb==0 blocks)
    if (tb == 0) {
        const int pr = tid >> 6;       // 0..3
        const int cc = c0 + (tid & 63);
        const int prow = (pr < 2) ? pr : (4098 + (pr - 2));
        const int tmod = (pr < 2) ? (6 + pr) : (pr - 2);   // (t&7) of the pad row
        aTb[(size_t)prow * CH + (cc ^ (tmod << 3))] = 0;
    }
}

// k2: per (b, 64-t tile): linear 34 KB staging of aT rows [t0, t0+68) (swizzle
// pre-baked), r9-style pipelined K-loop (weights from L2), in-register depthwise
// fold, LDS transpose epilogue with exact f32 residual from x.
// sA row r <-> global t = t0 + r - 2; swizzle of row r = ((r+6)&7)<<3.
__global__ __launch_bounds__(256, 3)
void gemm_kernel(const uint16_t* __restrict__ aT, const float* __restrict__ x,
                 float* __restrict__ out) {
    __shared__ __attribute__((aligned(16))) uint16_t sA[68 * CH];      // 34816 B
    __shared__ __attribute__((aligned(16))) float    sS[4 * 16 * SST]; // 17408 B

    const int tid  = threadIdx.x;
    const int lane = tid & 63;
    const int wid  = tid >> 6;
    const int b    = blockIdx.y;
    const int t0   = blockIdx.x * TN;

    const float* __restrict__ xb = x + (size_t)b * CH * TLEN;
    float* __restrict__ ob = out + (size_t)b * CH * TLEN;

    // ---- staging: linear copy, 2176 16B chunks ----
    {
        const u16x8* gsrc = (const u16x8*)(aT + (size_t)b * TPAD * CH + (size_t)t0 * CH);
        u16x8* ldst = (u16x8*)sA;
#pragma unroll
        for (int i = 0; i < 8; ++i) ldst[tid + i * 256] = gsrc[tid + i * 256];
        if (tid < 128) ldst[tid + 2048] = gsrc[tid + 2048];
    }
    __syncthreads();

    f32x4 acc[4][4];
    const f32x4 vzero = {0.f, 0.f, 0.f, 0.f};
#pragma unroll
    for (int mi = 0; mi < 4; ++mi)
#pragma unroll
        for (int ni = 0; ni < 4; ++ni) acc[mi][ni] = vzero;

    const int m0   = wid * 64;
    const int colt = lane & 15;
    const int kgrp = (lane >> 4) * 8;

    // ---- K loop, 1-deep ping-pong; weights global (L2), a from sA ----
    // B-frag for tile-local tt = ni*16+colt: row = tt+2, swz = (tt&7)<<3 = (colt&7)<<3
    const int swzB = (colt & 7) << 3;
    int rowB[4];
#pragma unroll
    for (int ni = 0; ni < 4; ++ni) rowB[ni] = (ni * 16 + colt + 2) * CH;

    bf16x8 afb[2][4], bfb[2][4];
#pragma unroll
    for (int mi = 0; mi < 4; ++mi) {
        const int co = m0 + mi * 16 + colt;
        afb[0][mi] = *(const bf16x8*)(g_w1eff + co * CH + kgrp);
    }
#pragma unroll
    for (int ni = 0; ni < 4; ++ni)
        bfb[0][ni] = *(const bf16x8*)(&sA[rowB[ni] + (kgrp ^ swzB)]);
#pragma unroll
    for (int s = 0; s < 8; ++s) {
        const int cur = s & 1, nxt = cur ^ 1;
        if (s < 7) {
            const int kk = (s + 1) * 32;
#pragma unroll
            for (int mi = 0; mi < 4; ++mi) {
                const int co = m0 + mi * 16 + colt;
                afb[nxt][mi] = *(const bf16x8*)(g_w1eff + co * CH + kk + kgrp);
            }
            const int cin = kk + kgrp;
#pragma unroll
            for (int ni = 0; ni < 4; ++ni)
                bfb[nxt][ni] = *(const bf16x8*)(&sA[rowB[ni] + (cin ^ swzB)]);
        }
#pragma unroll
        for (int mi = 0; mi < 4; ++mi)
#pragma unroll
            for (int ni = 0; ni < 4; ++ni)
                acc[mi][ni] = __builtin_amdgcn_mfma_f32_16x16x32_bf16(afb[cur][mi], bfb[cur][ni], acc[mi][ni], 0, 0, 0);
    }

    // ---- phase A: depthwise + bias folded into acc ----
    // element (tt+k-2) -> sA row tt+k, swz = ((tt+k+6)&7)<<3 = ((colt+k+6)&7)<<3
    const int rg = (lane >> 4) * 4;
    int swzA[5];
#pragma unroll
    for (int k = 0; k < 5; ++k) swzA[k] = ((colt + k + 6) & 7) << 3;
#pragma unroll
    for (int mi = 0; mi < 4; ++mi) {
        const int c = m0 + mi * 16 + rg;
        const f32x4 tp0 = *(const f32x4*)(g_tap + 0 * CH + c);
        const f32x4 tp1 = *(const f32x4*)(g_tap + 1 * CH + c);
        const f32x4 tp2 = *(const f32x4*)(g_tap + 2 * CH + c);
        const f32x4 tp3 = *(const f32x4*)(g_tap + 3 * CH + c);
        const f32x4 tp4 = *(const f32x4*)(g_tap + 4 * CH + c);
        const f32x4 bsv = *(const f32x4*)(g_bias + c);
#pragma unroll
        for (int ni = 0; ni < 4; ++ni) {
            const int t = ni * 16 + colt;
            u16x4 a0 = *(const u16x4*)(&sA[(t + 0) * CH + (c ^ swzA[0])]);
            u16x4 a1 = *(const u16x4*)(&sA[(t + 1) * CH + (c ^ swzA[1])]);
            u16x4 a2 = *(const u16x4*)(&sA[(t + 2) * CH + (c ^ swzA[2])]);
            u16x4 a3 = *(const u16x4*)(&sA[(t + 3) * CH + (c ^ swzA[3])]);
            u16x4 a4 = *(const u16x4*)(&sA[(t + 4) * CH + (c ^ swzA[4])]);
#pragma unroll
            for (int r = 0; r < 4; ++r) {
                float d = tp0[r] * bf16_to_f32(a0[r]);
                d = fmaf(tp1[r], bf16_to_f32(a1[r]), d);
                d = fmaf(tp2[r], bf16_to_f32(a2[r]), d);
                d = fmaf(tp3[r], bf16_to_f32(a3[r]), d);
                d = fmaf(tp4[r], bf16_to_f32(a4[r]), d);
                acc[mi][ni][r] += d + bsv[r];
            }
        }
    }

    // ---- phase B: wave-private transpose; exact f32 residual from x ----
    float* __restrict__ sw = sS + wid * (16 * SST);
    const int ci = lane >> 2;          // 0..15 channel-local
    const int q  = lane & 3;           // 0..3 -> 16 t each

#pragma unroll
    for (int mi = 0; mi < 4; ++mi) {
        const int cc = m0 + mi * 16 + ci;
        const float* xrow = xb + (size_t)cc * TLEN + t0 + q * 16;
        f32x4 xv0 = *(const f32x4*)(xrow + 0);
        f32x4 xv1 = *(const f32x4*)(xrow + 4);
        f32x4 xv2 = *(const f32x4*)(xrow + 8);
        f32x4 xv3 = *(const f32x4*)(xrow + 12);
#pragma unroll
        for (int ni = 0; ni < 4; ++ni) {
            const int t = ni * 16 + colt;
#pragma unroll
            for (int r = 0; r < 4; ++r) sw[(rg + r) * SST + t] = acc[mi][ni][r];
        }
        float* orow = ob + (size_t)cc * TLEN + t0 + q * 16;
        const float* srow = sw + ci * SST + q * 16;
        f32x4 s0 = *(const f32x4*)(srow + 0);
        f32x4 s1 = *(const f32x4*)(srow + 4);
        f32x4 s2 = *(const f32x4*)(srow + 8);
        f32x4 s3 = *(const f32x4*)(srow + 12);
        *(f32x4*)(orow + 0)  = s0 + xv0;
        *(f32x4*)(orow + 4)  = s1 + xv1;
        *(f32x4*)(orow + 8)  = s2 + xv2;
        *(f32x4*)(orow + 12) = s3 + xv3;
    }
}

extern "C" void kernel_launch(void* const* d_in, const int* in_sizes, int n_in,
                              void* d_out, int out_size, void* d_ws, size_t ws_size,
                              hipStream_t stream) {
    const float* x  = (const float*)d_in[0];
    const float* w1 = (const float*)d_in[1];
    const float* b1 = (const float*)d_in[2];
    const float* w3 = (const float*)d_in[3];
    const float* b3 = (const float*)d_in[4];
    const float* w5 = (const float*)d_in[5];
    const float* b5 = (const float*)d_in[6];
    const float* wc = (const float*)d_in[7];
    const float* bc = (const float*)d_in[8];
    float* out = (float*)d_out;
    uint16_t* aT = (uint16_t*)d_ws;    // 32*4100*256*2 B = 67.2 MB

    prep_kernel<<<dim3(CH), dim3(CH), 0, stream>>>(w1, b1, w3, b3, w5, b5, wc, bc);
    gelu_tr_kernel<<<dim3(TLEN / 64, CH / 64, BATCH), dim3(256), 0, stream>>>(x, aT);
    gemm_kernel<<<dim3(TLEN / TN, BATCH), dim3(256), 0, stream>>>(aT, x, out);
}